// Round 11
// baseline (208.580 us; speedup 1.0000x reference)
//
#include <hip/hip_runtime.h>
#include <hip/hip_bf16.h>

#define NN 4096
#define NFEAT 512
#define NHID 64
#define NHEAD 8
#define NCLASS 16
#define CAP 192
#define LALPHA 0.2f

#define SZ2 (NHEAD*2*NHID)   // a_heads
#define SZ3 (NHEAD*NHID)     // b_heads
#define SZ4 (NFEAT*NCLASS)   // W_out
#define SZ5 (2*NCLASS)       // a_out
#define SZ6 (NCLASS)         // b_out
#define NSMALL (SZ2+SZ3+SZ4+SZ5+SZ6)
#define NZERO (NN*NN/32 + NN + NHEAD*NHID + NCLASS)

typedef __attribute__((ext_vector_type(8))) short bf16x8;
typedef __attribute__((ext_vector_type(4))) float f32x4;
typedef __attribute__((ext_vector_type(8))) unsigned short u16x8;

// ---------- helpers ----------
__device__ __forceinline__ float b2f(unsigned short h) {
    return __uint_as_float(((unsigned int)h) << 16);
}
__device__ __forceinline__ unsigned short f2b(float f) {
    unsigned int u = __float_as_uint(f);
    unsigned int r = (u + 0x7fffu + ((u >> 16) & 1u)) >> 16;
    return (unsigned short)r;
}
__device__ __forceinline__ float waveMax(float v) {
#pragma unroll
    for (int m = 32; m >= 1; m >>= 1) v = fmaxf(v, __shfl_xor(v, m, 64));
    return v;
}
__device__ __forceinline__ float waveSum(float v) {
#pragma unroll
    for (int m = 32; m >= 1; m >>= 1) v += __shfl_xor(v, m, 64);
    return v;
}
__device__ __forceinline__ float lrelu(float e) {
    return e >= 0.f ? e : LALPHA * e;
}

// ---------- prep: W-transpose + zero + feature/small casts ----------
__global__ void __launch_bounds__(256)
k_prep(const void* __restrict__ f, const void* __restrict__ Wh_,
       const void* __restrict__ ah_, const void* __restrict__ bh_,
       const void* __restrict__ Wo_, const void* __restrict__ ao_,
       const void* __restrict__ bo_,
       unsigned short* __restrict__ featb,
       unsigned short* __restrict__ Wtb,
       float* __restrict__ smallf,
       unsigned int* __restrict__ zbase) {
    __shared__ int sbf;
    int t = threadIdx.x;
    if (t < 64) {
        unsigned int w = ((const unsigned int*)f)[t];
        unsigned int lo = w & 0xffffu, e = (lo >> 7) & 0xffu;
        unsigned long long bal = __ballot(lo == 0u || (e >= 100u && e <= 140u));
        if (t == 0) sbf = (__popcll(bal) >= 40);
    }
    __syncthreads();
    bool bf = (sbf != 0);
    if (blockIdx.x < 128) {
        __shared__ float tile[64][33];
        int h = blockIdx.x >> 4, k0 = (blockIdx.x & 15) * 32;
        int n = t & 63, kh = t >> 6;
#pragma unroll
        for (int i = 0; i < 8; ++i) {
            int kk = kh * 8 + i;
            int si = (h << 15) + (k0 + kk) * NHID + n;
            float v = bf ? b2f(((const unsigned short*)Wh_)[si])
                         : ((const float*)Wh_)[si];
            tile[n][kk] = v;
        }
        __syncthreads();
        int n2 = t >> 2, kk0 = (t & 3) * 8;
        u16x8 o;
#pragma unroll
        for (int i = 0; i < 8; ++i) o[i] = f2b(tile[n2][kk0 + i]);
        *(u16x8*)&Wtb[(size_t)((h << 6) + n2) * NFEAT + k0 + kk0] = o;
    } else {
        const int NF8 = NN * NFEAT / 8;
        int i = (blockIdx.x - 128) * 256 + t;
        int stride = (gridDim.x - 128) * 256;
        const int TOT = NZERO + NF8 + NSMALL;
        for (; i < TOT; i += stride) {
            if (i < NZERO) {
                zbase[i] = 0u;
            } else if (i < NZERO + NF8) {
                int r = i - NZERO;
                if (bf) {
                    *(u16x8*)&featb[r * 8] = ((const u16x8*)f)[r];
                } else {
                    float4 lo = ((const float4*)f)[r * 2];
                    float4 hi = ((const float4*)f)[r * 2 + 1];
                    u16x8 o;
                    o[0] = f2b(lo.x); o[1] = f2b(lo.y); o[2] = f2b(lo.z); o[3] = f2b(lo.w);
                    o[4] = f2b(hi.x); o[5] = f2b(hi.y); o[6] = f2b(hi.z); o[7] = f2b(hi.w);
                    *(u16x8*)&featb[r * 8] = o;
                }
            } else {
                int r = i - NZERO - NF8;
                const void* sp; int off;
                if (r < SZ2)                        { sp = ah_; off = r; }
                else if (r < SZ2 + SZ3)             { sp = bh_; off = r - SZ2; }
                else if (r < SZ2 + SZ3 + SZ4)       { sp = Wo_; off = r - SZ2 - SZ3; }
                else if (r < SZ2 + SZ3 + SZ4 + SZ5) { sp = ao_; off = r - SZ2 - SZ3 - SZ4; }
                else                                { sp = bo_; off = r - SZ2 - SZ3 - SZ4 - SZ5; }
                smallf[r] = bf ? b2f(((const unsigned short*)sp)[off])
                               : ((const float*)sp)[off];
            }
        }
    }
}

// ---------- merged: CSR build (blocks [0,csb)) + MFMA gemm1 (blocks [csb, csb+256)) ----------
// Independent work co-scheduled in one launch: CSR atomics overlap GEMM loads/MFMA.
__global__ void __launch_bounds__(256)
k_csr_gemm1(const int* __restrict__ e32, int E, int csb,
            unsigned int* __restrict__ bits,
            int* __restrict__ deg, int* __restrict__ csr,
            const unsigned short* __restrict__ Ab,   // [NN][NFEAT] bf16
            const unsigned short* __restrict__ Wtb,  // [NHEAD][NHID][NFEAT] bf16
            const float* __restrict__ ah,            // [NHEAD][2*NHID]
            unsigned short* __restrict__ Hb,         // [NHEAD][NN][NHID] bf16
            float* __restrict__ s1, float* __restrict__ s2,   // [NHEAD][NN]
            float* __restrict__ cm1) {               // [NHEAD][NHID]
    int t = threadIdx.x;
    if ((int)blockIdx.x < csb) {
        // ---- CSR build ----
        __shared__ int s64f;
        if (t < 64) {
            unsigned long long bal = __ballot(e32[2 * t + 1] == 0);
            if (t == 0) s64f = (__popcll(bal) >= 48);
        }
        __syncthreads();
        int i = blockIdx.x * 256 + t;
        if (i < E) {
            int s, tt;
            if (s64f) { s = e32[2 * i]; tt = e32[2 * (E + i)]; }
            else      { s = e32[i];     tt = e32[E + i]; }
            s &= (NN - 1); tt &= (NN - 1);
            unsigned int pos = (unsigned int)s * NN + (unsigned int)tt;
            unsigned int mask = 1u << (pos & 31u);
            unsigned int old = atomicOr(&bits[pos >> 5], mask);
            if (!(old & mask)) {
                int j = atomicAdd(&deg[s], 1);
                if (j < CAP) csr[s * CAP + j] = tt;
            }
        }
        return;
    }
    // ---- gemm1: block b in [0,256), h = b>>5, bx = b&31 ----
    __shared__ float cms[64];
    if (t < 64) cms[t] = 0.f;
    __syncthreads();
    int b = blockIdx.x - csb;
    int h = b >> 5;
    int m0 = (b & 31) * 128 + (t >> 6) * 32;
    int l = t & 63;
    int quad = l >> 4, l16 = l & 15;
    f32x4 acc[2][4] = {};
    const unsigned short* a0p = Ab + (size_t)(m0 + l16) * NFEAT + quad * 8;
    const unsigned short* a1p = a0p + 16 * NFEAT;
    const unsigned short* bp  = Wtb + ((size_t)h << 15) + (size_t)l16 * NFEAT + quad * 8;
#pragma unroll 4
    for (int k0 = 0; k0 < NFEAT; k0 += 32) {
        bf16x8 a0 = *(const bf16x8*)(a0p + k0);
        bf16x8 a1 = *(const bf16x8*)(a1p + k0);
#pragma unroll
        for (int nt = 0; nt < 4; ++nt) {
            bf16x8 bb = *(const bf16x8*)(bp + (size_t)nt * 16 * NFEAT + k0);
            acc[0][nt] = __builtin_amdgcn_mfma_f32_16x16x32_bf16(a0, bb, acc[0][nt], 0, 0, 0);
            acc[1][nt] = __builtin_amdgcn_mfma_f32_16x16x32_bf16(a1, bb, acc[1][nt], 0, 0, 0);
        }
    }
    const float* av = ah + h * 2 * NHID;
    float p1[2][4] = {}, p2[2][4] = {};
#pragma unroll
    for (int rh = 0; rh < 2; ++rh) {
#pragma unroll
        for (int nt = 0; nt < 4; ++nt) {
            int col = nt * 16 + l16;
            float av1 = av[col], av2 = av[NHID + col];
            float csum = 0.f;
#pragma unroll
            for (int r = 0; r < 4; ++r) {
                float v = acc[rh][nt][r];
                int row = m0 + rh * 16 + quad * 4 + r;
                Hb[(((size_t)h << 12) + row) * NHID + col] = f2b(v);
                p1[rh][r] += v * av1;
                p2[rh][r] += v * av2;
                csum += v;
            }
            atomicAdd(&cms[col], csum);
        }
    }
#pragma unroll
    for (int m = 8; m >= 1; m >>= 1)
#pragma unroll
        for (int rh = 0; rh < 2; ++rh)
#pragma unroll
            for (int r = 0; r < 4; ++r) {
                p1[rh][r] += __shfl_xor(p1[rh][r], m, 64);
                p2[rh][r] += __shfl_xor(p2[rh][r], m, 64);
            }
    if (l16 == 0) {
#pragma unroll
        for (int rh = 0; rh < 2; ++rh)
#pragma unroll
            for (int r = 0; r < 4; ++r) {
                int row = m0 + rh * 16 + quad * 4 + r;
                s1[(h << 12) + row] = p1[rh][r];
                s2[(h << 12) + row] = p2[rh][r];
            }
    }
    __syncthreads();
    if (t < 64) atomicAdd(&cm1[h * NHID + t], cms[t]);
}

// ---------- layer-1: softmax + SpMM(bf16 H) + bias + ELU + concat ----------
// wave per (n,h), head-major order. Gather: 8 lanes/neighbor x u16x8.
__global__ void __launch_bounds__(256)
k_attn1(const int* __restrict__ deg, const int* __restrict__ csr,
        const float* __restrict__ s1, const float* __restrict__ s2,
        const unsigned short* __restrict__ Hb, const float* __restrict__ bh,
        const float* __restrict__ cm1, float* __restrict__ X) {
    __shared__ float2 wts[4][CAP];
    int wid = threadIdx.x >> 6, lane = threadIdx.x & 63;
    int idx = blockIdx.x * 4 + wid;
    int n = idx & (NN - 1), h = idx >> 12;
    int e8 = lane & 7, g = lane >> 3;
    int d = min(deg[n], CAP);
    float acc[8] = {};
    float den = 1.f;
    if (d > 0) {
        float s1n = s1[idx];
        const float* s2h = s2 + ((size_t)h << 12);
        const int* row = csr + (size_t)n * CAP;
        int t0 = (lane < d)       ? (row[lane]       & (NN - 1)) : 0;
        int t1 = (lane + 64 < d)  ? (row[lane + 64]  & (NN - 1)) : 0;
        int t2 = (lane + 128 < d) ? (row[lane + 128] & (NN - 1)) : 0;
        float e0 = (lane < d)       ? lrelu(s1n + s2h[t0]) : -1e30f;
        float e1 = (lane + 64 < d)  ? lrelu(s1n + s2h[t1]) : -1e30f;
        float e2 = (lane + 128 < d) ? lrelu(s1n + s2h[t2]) : -1e30f;
        float m = waveMax(fmaxf(e0, fmaxf(e1, e2)));
        float w0 = (lane < d)       ? __expf(e0 - m) : 0.f;
        float w1 = (lane + 64 < d)  ? __expf(e1 - m) : 0.f;
        float w2 = (lane + 128 < d) ? __expf(e2 - m) : 0.f;
        den = waveSum(w0 + w1 + w2);
        wts[wid][lane]       = make_float2(w0, __int_as_float(t0 << 6));
        wts[wid][lane + 64]  = make_float2(w1, __int_as_float(t1 << 6));
        wts[wid][lane + 128] = make_float2(w2, __int_as_float(t2 << 6));
        const unsigned short* Hp = Hb + (((size_t)h << 12) * NHID) + e8 * 8;
#pragma unroll 2
        for (int j = g; j < d; j += 8) {
            float2 p = wts[wid][j];
            u16x8 v = *(const u16x8*)(Hp + __float_as_int(p.y));
#pragma unroll
            for (int i = 0; i < 8; ++i) acc[i] += p.x * b2f(v[i]);
        }
#pragma unroll
        for (int m2 = 8; m2 <= 32; m2 <<= 1)
#pragma unroll
            for (int i = 0; i < 8; ++i) acc[i] += __shfl_xor(acc[i], m2, 64);
    }
    if (lane < 8) {
        float o[8];
        if (d == 0) {
            const float* c = cm1 + h * NHID + lane * 8;
#pragma unroll
            for (int i = 0; i < 8; ++i) o[i] = c[i] * (1.0f / NN);
        } else {
            float rden = 1.0f / den;
#pragma unroll
            for (int i = 0; i < 8; ++i) o[i] = acc[i] * rden;
        }
        const float* b8p = bh + h * NHID + lane * 8;
#pragma unroll
        for (int i = 0; i < 8; ++i) {
            float v = o[i] + b8p[i];
            o[i] = v > 0.f ? v : __expf(v) - 1.f;     // ELU
        }
        float* xp = &X[(size_t)n * NFEAT + h * NHID + lane * 8];
        *(float4*)xp       = make_float4(o[0], o[1], o[2], o[3]);
        *(float4*)(xp + 4) = make_float4(o[4], o[5], o[6], o[7]);
    }
}

// ---------- gemm2 + fused scores2 + colmean2 ----------
__global__ void __launch_bounds__(256)
k_gemm2f(const float* __restrict__ X, const float* __restrict__ Wo,
         const float* __restrict__ ao, float* __restrict__ out2,
         float* __restrict__ s1o, float* __restrict__ s2o,
         float* __restrict__ cm2) {
    __shared__ float cms[16];
    int t = threadIdx.x;
    if (t < 16) cms[t] = 0.f;
    __syncthreads();
    int wid = t >> 6, lane = t & 63;
    int n = blockIdx.x * 4 + wid;
    int c = lane & 15, sub = lane >> 4;
    const float* xr = X + (size_t)n * NFEAT + sub * 128;
    const float* wr = Wo + sub * 128 * NCLASS + c;
    float acc = 0.f;
#pragma unroll 8
    for (int kk = 0; kk < 128; ++kk) acc += xr[kk] * wr[kk * NCLASS];
    acc += __shfl_xor(acc, 16, 64);
    acc += __shfl_xor(acc, 32, 64);
    if (lane < 16) out2[n * NCLASS + c] = acc;
    float r1 = acc * ao[c], r2 = acc * ao[NCLASS + c];
#pragma unroll
    for (int m = 8; m >= 1; m >>= 1) {
        r1 += __shfl_xor(r1, m, 16);
        r2 += __shfl_xor(r2, m, 16);
    }
    if (lane == 0) { s1o[n] = r1; s2o[n] = r2; }
    if (lane < 16) atomicAdd(&cms[c], acc);
    __syncthreads();
    if (t < 16) atomicAdd(&cm2[t], cms[t]);
}

// ---------- layer-2: softmax + SpMM + bias + log_softmax ----------
__global__ void __launch_bounds__(256)
k_attn2(const int* __restrict__ deg, const int* __restrict__ csr,
        const float* __restrict__ s1o, const float* __restrict__ s2o,
        const float* __restrict__ out2, const float* __restrict__ bo,
        const float* __restrict__ cm2, float* __restrict__ outp) {
    __shared__ float2 wts[4][CAP];
    __shared__ float o2s[4][16];
    int wid = threadIdx.x >> 6, lane = threadIdx.x & 63;
    int n = blockIdx.x * 4 + wid;
    int c = lane & 15;
    int d = min(deg[n], CAP);
    float val;
    if (d == 0) {
        val = cm2[c] * (1.0f / NN);
    } else {
        float s1n = s1o[n];
        const int* row = csr + (size_t)n * CAP;
        int t0 = (lane < d)       ? (row[lane]       & (NN - 1)) : 0;
        int t1 = (lane + 64 < d)  ? (row[lane + 64]  & (NN - 1)) : 0;
        int t2 = (lane + 128 < d) ? (row[lane + 128] & (NN - 1)) : 0;
        float e0 = (lane < d)       ? lrelu(s1n + s2o[t0]) : -1e30f;
        float e1 = (lane + 64 < d)  ? lrelu(s1n + s2o[t1]) : -1e30f;
        float e2 = (lane + 128 < d) ? lrelu(s1n + s2o[t2]) : -1e30f;
        float m = waveMax(fmaxf(e0, fmaxf(e1, e2)));
        float w0 = (lane < d)       ? __expf(e0 - m) : 0.f;
        float w1 = (lane + 64 < d)  ? __expf(e1 - m) : 0.f;
        float w2 = (lane + 128 < d) ? __expf(e2 - m) : 0.f;
        float den = waveSum(w0 + w1 + w2);
        wts[wid][lane]       = make_float2(w0, __int_as_float(t0 << 4));
        wts[wid][lane + 64]  = make_float2(w1, __int_as_float(t1 << 4));
        wts[wid][lane + 128] = make_float2(w2, __int_as_float(t2 << 4));
        int g2 = lane >> 2, q = lane & 3;
        float a4[4] = {};
        for (int j = g2; j < d; j += 16) {
            float2 p = wts[wid][j];
            float4 v = *(const float4*)(out2 + __float_as_int(p.y) + q * 4);
            a4[0] += p.x * v.x; a4[1] += p.x * v.y;
            a4[2] += p.x * v.z; a4[3] += p.x * v.w;
        }
#pragma unroll
        for (int m2 = 4; m2 <= 32; m2 <<= 1)
#pragma unroll
            for (int i = 0; i < 4; ++i) a4[i] += __shfl_xor(a4[i], m2, 64);
        if (lane < 4)
            *(float4*)&o2s[wid][lane * 4] = make_float4(a4[0], a4[1], a4[2], a4[3]);
        val = o2s[wid][c] / den;
    }
    val += bo[c];
    float mx = val;
#pragma unroll
    for (int m = 8; m >= 1; m >>= 1) mx = fmaxf(mx, __shfl_xor(mx, m, 16));
    float se = __expf(val - mx);
#pragma unroll
    for (int m = 8; m >= 1; m >>= 1) se += __shfl_xor(se, m, 16);
    float res = val - mx - __logf(se);
    if (lane < 16) outp[n * NCLASS + lane] = res;
}

extern "C" void kernel_launch(void* const* d_in, const int* in_sizes, int n_in,
                              void* d_out, int out_size, void* d_ws, size_t ws_size,
                              hipStream_t stream) {
    const void* features = d_in[0];
    const int*  edges    = (const int*)d_in[1];
    const void* W_heads  = d_in[2];
    const void* a_heads  = d_in[3];
    const void* b_heads  = d_in[4];
    const void* W_out    = d_in[5];
    const void* a_out    = d_in[6];
    const void* b_out    = d_in[7];
    int E = in_sizes[1] / 2;

    // ---- workspace layout (4B units) ----
    unsigned int* bits = (unsigned int*)d_ws;                  // NN*NN/32
    int*   deg  = (int*)(bits + (NN * NN / 32));               // NN
    float* cm1  = (float*)(deg + NN);                          // NHEAD*NHID
    float* cm2  = cm1 + NHEAD * NHID;                          // NCLASS (zero region end)
    int*   csr  = (int*)(cm2 + NCLASS);                        // NN*CAP
    float* s1   = (float*)(csr + NN * CAP);                    // NHEAD*NN
    float* s2   = s1 + NHEAD * NN;                             // NHEAD*NN
    float* X    = s2 + NHEAD * NN;                             // NN*NFEAT
    float* out2 = X + (size_t)NN * NFEAT;                      // NN*NCLASS
    float* s1o  = out2 + NN * NCLASS;                          // NN
    float* s2o  = s1o + NN;                                    // NN
    unsigned short* Hb    = (unsigned short*)(s2o + NN);       // NHEAD*NN*NHID bf16
    unsigned short* featb = Hb + (size_t)NHEAD * NN * NHID;    // NN*NFEAT bf16
    unsigned short* Wtb   = featb + (size_t)NN * NFEAT;        // NHEAD*NHID*NFEAT bf16
    float* smallf = (float*)(Wtb + NHEAD * NHID * NFEAT);      // NSMALL fp32
    float* ahf = smallf;
    float* bhf = ahf + SZ2;
    float* Wof = bhf + SZ3;
    float* aof = Wof + SZ4;
    float* bof = aof + SZ5;
    float* outp = (float*)d_out;

    int csb = (E + 255) / 256;
    hipLaunchKernelGGL(k_prep, dim3(2048), dim3(256), 0, stream,
                       features, W_heads, a_heads, b_heads, W_out, a_out, b_out,
                       featb, Wtb, smallf, bits);
    hipLaunchKernelGGL(k_csr_gemm1, dim3(csb + 256), dim3(256), 0, stream,
                       edges, E, csb, bits, deg, csr,
                       featb, Wtb, ahf, Hb, s1, s2, cm1);
    hipLaunchKernelGGL(k_attn1, dim3(NN * NHEAD / 4), dim3(256), 0, stream,
                       deg, csr, s1, s2, Hb, bhf, cm1, X);
    hipLaunchKernelGGL(k_gemm2f, dim3(NN / 4), dim3(256), 0, stream,
                       X, Wof, aof, out2, s1o, s2o, cm2);
    hipLaunchKernelGGL(k_attn2, dim3(NN / 4), dim3(256), 0, stream,
                       deg, csr, s1o, s2o, out2, bof, cm2, outp);
}

// Round 12
// 193.461 us; speedup vs baseline: 1.0782x; 1.0782x over previous
//
#include <hip/hip_runtime.h>
#include <hip/hip_bf16.h>

#define NN 4096
#define NFEAT 512
#define NHID 64
#define NHEAD 8
#define NCLASS 16
#define CAP 192
#define LALPHA 0.2f

#define SZ2 (NHEAD*2*NHID)   // a_heads
#define SZ3 (NHEAD*NHID)     // b_heads
#define SZ4 (NFEAT*NCLASS)   // W_out
#define SZ5 (2*NCLASS)       // a_out
#define SZ6 (NCLASS)         // b_out
#define NSMALL (SZ2+SZ3+SZ4+SZ5+SZ6)
#define NZERO (NN*NN/32 + NN + NHEAD*NHID + NCLASS)

typedef __attribute__((ext_vector_type(8))) short bf16x8;
typedef __attribute__((ext_vector_type(4))) float f32x4;
typedef __attribute__((ext_vector_type(8))) unsigned short u16x8;

// ---------- helpers ----------
__device__ __forceinline__ float b2f(unsigned short h) {
    return __uint_as_float(((unsigned int)h) << 16);
}
__device__ __forceinline__ unsigned short f2b(float f) {
    unsigned int u = __float_as_uint(f);
    unsigned int r = (u + 0x7fffu + ((u >> 16) & 1u)) >> 16;
    return (unsigned short)r;
}
__device__ __forceinline__ float waveMax(float v) {
#pragma unroll
    for (int m = 32; m >= 1; m >>= 1) v = fmaxf(v, __shfl_xor(v, m, 64));
    return v;
}
__device__ __forceinline__ float waveSum(float v) {
#pragma unroll
    for (int m = 32; m >= 1; m >>= 1) v += __shfl_xor(v, m, 64);
    return v;
}
__device__ __forceinline__ float lrelu(float e) {
    return e >= 0.f ? e : LALPHA * e;
}

// ---------- prep: W-transpose + zero + feature/small casts ----------
__global__ void __launch_bounds__(256)
k_prep(const void* __restrict__ f, const void* __restrict__ Wh_,
       const void* __restrict__ ah_, const void* __restrict__ bh_,
       const void* __restrict__ Wo_, const void* __restrict__ ao_,
       const void* __restrict__ bo_,
       unsigned short* __restrict__ featb,
       unsigned short* __restrict__ Wtb,
       float* __restrict__ smallf,
       unsigned int* __restrict__ zbase) {
    __shared__ int sbf;
    int t = threadIdx.x;
    if (t < 64) {
        unsigned int w = ((const unsigned int*)f)[t];
        unsigned int lo = w & 0xffffu, e = (lo >> 7) & 0xffu;
        unsigned long long bal = __ballot(lo == 0u || (e >= 100u && e <= 140u));
        if (t == 0) sbf = (__popcll(bal) >= 40);
    }
    __syncthreads();
    bool bf = (sbf != 0);
    if (blockIdx.x < 128) {
        __shared__ float tile[64][33];
        int h = blockIdx.x >> 4, k0 = (blockIdx.x & 15) * 32;
        int n = t & 63, kh = t >> 6;
#pragma unroll
        for (int i = 0; i < 8; ++i) {
            int kk = kh * 8 + i;
            int si = (h << 15) + (k0 + kk) * NHID + n;
            float v = bf ? b2f(((const unsigned short*)Wh_)[si])
                         : ((const float*)Wh_)[si];
            tile[n][kk] = v;
        }
        __syncthreads();
        int n2 = t >> 2, kk0 = (t & 3) * 8;
        u16x8 o;
#pragma unroll
        for (int i = 0; i < 8; ++i) o[i] = f2b(tile[n2][kk0 + i]);
        *(u16x8*)&Wtb[(size_t)((h << 6) + n2) * NFEAT + k0 + kk0] = o;
    } else {
        const int NF8 = NN * NFEAT / 8;
        int i = (blockIdx.x - 128) * 256 + t;
        int stride = (gridDim.x - 128) * 256;
        const int TOT = NZERO + NF8 + NSMALL;
        for (; i < TOT; i += stride) {
            if (i < NZERO) {
                zbase[i] = 0u;
            } else if (i < NZERO + NF8) {
                int r = i - NZERO;
                if (bf) {
                    *(u16x8*)&featb[r * 8] = ((const u16x8*)f)[r];
                } else {
                    float4 lo = ((const float4*)f)[r * 2];
                    float4 hi = ((const float4*)f)[r * 2 + 1];
                    u16x8 o;
                    o[0] = f2b(lo.x); o[1] = f2b(lo.y); o[2] = f2b(lo.z); o[3] = f2b(lo.w);
                    o[4] = f2b(hi.x); o[5] = f2b(hi.y); o[6] = f2b(hi.z); o[7] = f2b(hi.w);
                    *(u16x8*)&featb[r * 8] = o;
                }
            } else {
                int r = i - NZERO - NF8;
                const void* sp; int off;
                if (r < SZ2)                        { sp = ah_; off = r; }
                else if (r < SZ2 + SZ3)             { sp = bh_; off = r - SZ2; }
                else if (r < SZ2 + SZ3 + SZ4)       { sp = Wo_; off = r - SZ2 - SZ3; }
                else if (r < SZ2 + SZ3 + SZ4 + SZ5) { sp = ao_; off = r - SZ2 - SZ3 - SZ4; }
                else                                { sp = bo_; off = r - SZ2 - SZ3 - SZ4 - SZ5; }
                smallf[r] = bf ? b2f(((const unsigned short*)sp)[off])
                               : ((const float*)sp)[off];
            }
        }
    }
}

// ---------- dedup edges, build padded CSR (inline int64 detection) ----------
__global__ void k_build_csr(const int* __restrict__ e32, int E,
                            unsigned int* __restrict__ bits,
                            int* __restrict__ deg, int* __restrict__ csr) {
    __shared__ int s64f;
    int t = threadIdx.x;
    if (t < 64) {
        unsigned long long bal = __ballot(e32[2 * t + 1] == 0);
        if (t == 0) s64f = (__popcll(bal) >= 48);
    }
    __syncthreads();
    int i = blockIdx.x * blockDim.x + t;
    if (i >= E) return;
    int s, tt;
    if (s64f) { s = e32[2 * i]; tt = e32[2 * (E + i)]; }
    else      { s = e32[i];     tt = e32[E + i]; }
    s &= (NN - 1); tt &= (NN - 1);
    unsigned int pos = (unsigned int)s * NN + (unsigned int)tt;
    unsigned int mask = 1u << (pos & 31u);
    unsigned int old = atomicOr(&bits[pos >> 5], mask);
    if (!(old & mask)) {
        int j = atomicAdd(&deg[s], 1);
        if (j < CAP) csr[s * CAP + j] = tt;
    }
}

// ---------- MFMA gemm1, K-split across 4 waves + fused scores1/colmean1 ----------
// grid 2048 (head-major: h = b>>8, 16 rows per block). Block 256 = 4 waves.
// Wave w computes K-chunk [w*128,(w+1)*128); LDS-reduce; wave 0 epilogue.
__global__ void __launch_bounds__(256)
k_gemm1m(const unsigned short* __restrict__ Ab,   // [NN][NFEAT] bf16
         const unsigned short* __restrict__ Wtb,  // [NHEAD][NHID][NFEAT] bf16
         const float* __restrict__ ah,            // [NHEAD][2*NHID]
         unsigned short* __restrict__ Hb,         // [NHEAD][NN][NHID] bf16
         float* __restrict__ s1, float* __restrict__ s2,   // [NHEAD][NN]
         float* __restrict__ cm1) {               // [NHEAD][NHID]
    __shared__ float red[3 * 64 * 20];            // 3 waves x 64 lanes x (16+4 pad)
    int t = threadIdx.x;
    int w = t >> 6, l = t & 63;
    int quad = l >> 4, l16 = l & 15;
    int h = blockIdx.x >> 8;
    int m0 = (blockIdx.x & 255) << 4;
    f32x4 acc[4] = {};
    const unsigned short* ap = Ab + (size_t)(m0 + l16) * NFEAT + w * 128 + quad * 8;
    const unsigned short* bp = Wtb + ((size_t)h << 15) + (size_t)l16 * NFEAT + w * 128 + quad * 8;
#pragma unroll
    for (int k0 = 0; k0 < 128; k0 += 32) {
        bf16x8 a = *(const bf16x8*)(ap + k0);
#pragma unroll
        for (int nt = 0; nt < 4; ++nt) {
            bf16x8 b = *(const bf16x8*)(bp + (size_t)nt * 16 * NFEAT + k0);
            acc[nt] = __builtin_amdgcn_mfma_f32_16x16x32_bf16(a, b, acc[nt], 0, 0, 0);
        }
    }
    if (w > 0) {
        int base = ((w - 1) * 64 + l) * 20;
#pragma unroll
        for (int nt = 0; nt < 4; ++nt)
            *(f32x4*)&red[base + nt * 4] = acc[nt];
    }
    __syncthreads();
    if (w > 0) return;
    // wave 0: sum partials
#pragma unroll
    for (int ww = 0; ww < 3; ++ww) {
        int base = (ww * 64 + l) * 20;
#pragma unroll
        for (int nt = 0; nt < 4; ++nt)
            acc[nt] += *(const f32x4*)&red[base + nt * 4];
    }
    // epilogue: Hb bf16 store + s1/s2 row-dots + colmean atomics
    const float* av = ah + h * 2 * NHID;
    float p1[4] = {}, p2[4] = {};
#pragma unroll
    for (int nt = 0; nt < 4; ++nt) {
        int col = nt * 16 + l16;
        float av1 = av[col], av2 = av[NHID + col];
        float csum = 0.f;
#pragma unroll
        for (int r = 0; r < 4; ++r) {
            float v = acc[nt][r];
            int row = m0 + quad * 4 + r;
            Hb[(((size_t)h << 12) + row) * NHID + col] = f2b(v);
            p1[r] += v * av1;
            p2[r] += v * av2;
            csum += v;
        }
        csum += __shfl_xor(csum, 16, 64);
        csum += __shfl_xor(csum, 32, 64);
        if (quad == 0) atomicAdd(&cm1[h * NHID + col], csum);
    }
#pragma unroll
    for (int m = 8; m >= 1; m >>= 1)
#pragma unroll
        for (int r = 0; r < 4; ++r) {
            p1[r] += __shfl_xor(p1[r], m, 64);
            p2[r] += __shfl_xor(p2[r], m, 64);
        }
    if (l16 == 0) {
#pragma unroll
        for (int r = 0; r < 4; ++r) {
            int row = m0 + quad * 4 + r;
            s1[(h << 12) + row] = p1[r];
            s2[(h << 12) + row] = p2[r];
        }
    }
}

// ---------- layer-1: softmax + SpMM(bf16 H) + bias + ELU + concat ----------
// wave per (n,h), head-major order. Gather: 8 lanes/neighbor x u16x8.
__global__ void __launch_bounds__(256)
k_attn1(const int* __restrict__ deg, const int* __restrict__ csr,
        const float* __restrict__ s1, const float* __restrict__ s2,
        const unsigned short* __restrict__ Hb, const float* __restrict__ bh,
        const float* __restrict__ cm1, float* __restrict__ X) {
    __shared__ float2 wts[4][CAP];
    int wid = threadIdx.x >> 6, lane = threadIdx.x & 63;
    int idx = blockIdx.x * 4 + wid;
    int n = idx & (NN - 1), h = idx >> 12;
    int e8 = lane & 7, g = lane >> 3;
    int d = min(deg[n], CAP);
    float acc[8] = {};
    float den = 1.f;
    if (d > 0) {
        float s1n = s1[idx];
        const float* s2h = s2 + ((size_t)h << 12);
        const int* row = csr + (size_t)n * CAP;
        int t0 = (lane < d)       ? (row[lane]       & (NN - 1)) : 0;
        int t1 = (lane + 64 < d)  ? (row[lane + 64]  & (NN - 1)) : 0;
        int t2 = (lane + 128 < d) ? (row[lane + 128] & (NN - 1)) : 0;
        float e0 = (lane < d)       ? lrelu(s1n + s2h[t0]) : -1e30f;
        float e1 = (lane + 64 < d)  ? lrelu(s1n + s2h[t1]) : -1e30f;
        float e2 = (lane + 128 < d) ? lrelu(s1n + s2h[t2]) : -1e30f;
        float m = waveMax(fmaxf(e0, fmaxf(e1, e2)));
        float w0 = (lane < d)       ? __expf(e0 - m) : 0.f;
        float w1 = (lane + 64 < d)  ? __expf(e1 - m) : 0.f;
        float w2 = (lane + 128 < d) ? __expf(e2 - m) : 0.f;
        den = waveSum(w0 + w1 + w2);
        wts[wid][lane]       = make_float2(w0, __int_as_float(t0 << 6));
        wts[wid][lane + 64]  = make_float2(w1, __int_as_float(t1 << 6));
        wts[wid][lane + 128] = make_float2(w2, __int_as_float(t2 << 6));
        const unsigned short* Hp = Hb + (((size_t)h << 12) * NHID) + e8 * 8;
#pragma unroll 2
        for (int j = g; j < d; j += 8) {
            float2 p = wts[wid][j];
            u16x8 v = *(const u16x8*)(Hp + __float_as_int(p.y));
#pragma unroll
            for (int i = 0; i < 8; ++i) acc[i] += p.x * b2f(v[i]);
        }
#pragma unroll
        for (int m2 = 8; m2 <= 32; m2 <<= 1)
#pragma unroll
            for (int i = 0; i < 8; ++i) acc[i] += __shfl_xor(acc[i], m2, 64);
    }
    if (lane < 8) {
        float o[8];
        if (d == 0) {
            const float* c = cm1 + h * NHID + lane * 8;
#pragma unroll
            for (int i = 0; i < 8; ++i) o[i] = c[i] * (1.0f / NN);
        } else {
            float rden = 1.0f / den;
#pragma unroll
            for (int i = 0; i < 8; ++i) o[i] = acc[i] * rden;
        }
        const float* b8p = bh + h * NHID + lane * 8;
#pragma unroll
        for (int i = 0; i < 8; ++i) {
            float v = o[i] + b8p[i];
            o[i] = v > 0.f ? v : __expf(v) - 1.f;     // ELU
        }
        float* xp = &X[(size_t)n * NFEAT + h * NHID + lane * 8];
        *(float4*)xp       = make_float4(o[0], o[1], o[2], o[3]);
        *(float4*)(xp + 4) = make_float4(o[4], o[5], o[6], o[7]);
    }
}

// ---------- gemm2 + fused scores2 + colmean2 ----------
__global__ void __launch_bounds__(256)
k_gemm2f(const float* __restrict__ X, const float* __restrict__ Wo,
         const float* __restrict__ ao, float* __restrict__ out2,
         float* __restrict__ s1o, float* __restrict__ s2o,
         float* __restrict__ cm2) {
    __shared__ float cms[16];
    int t = threadIdx.x;
    if (t < 16) cms[t] = 0.f;
    __syncthreads();
    int wid = t >> 6, lane = t & 63;
    int n = blockIdx.x * 4 + wid;
    int c = lane & 15, sub = lane >> 4;
    const float* xr = X + (size_t)n * NFEAT + sub * 128;
    const float* wr = Wo + sub * 128 * NCLASS + c;
    float acc = 0.f;
#pragma unroll 8
    for (int kk = 0; kk < 128; ++kk) acc += xr[kk] * wr[kk * NCLASS];
    acc += __shfl_xor(acc, 16, 64);
    acc += __shfl_xor(acc, 32, 64);
    if (lane < 16) out2[n * NCLASS + c] = acc;
    float r1 = acc * ao[c], r2 = acc * ao[NCLASS + c];
#pragma unroll
    for (int m = 8; m >= 1; m >>= 1) {
        r1 += __shfl_xor(r1, m, 16);
        r2 += __shfl_xor(r2, m, 16);
    }
    if (lane == 0) { s1o[n] = r1; s2o[n] = r2; }
    if (lane < 16) atomicAdd(&cms[c], acc);
    __syncthreads();
    if (t < 16) atomicAdd(&cm2[t], cms[t]);
}

// ---------- layer-2: softmax + SpMM + bias + log_softmax ----------
__global__ void __launch_bounds__(256)
k_attn2(const int* __restrict__ deg, const int* __restrict__ csr,
        const float* __restrict__ s1o, const float* __restrict__ s2o,
        const float* __restrict__ out2, const float* __restrict__ bo,
        const float* __restrict__ cm2, float* __restrict__ outp) {
    __shared__ float2 wts[4][CAP];
    __shared__ float o2s[4][16];
    int wid = threadIdx.x >> 6, lane = threadIdx.x & 63;
    int n = blockIdx.x * 4 + wid;
    int c = lane & 15;
    int d = min(deg[n], CAP);
    float val;
    if (d == 0) {
        val = cm2[c] * (1.0f / NN);
    } else {
        float s1n = s1o[n];
        const int* row = csr + (size_t)n * CAP;
        int t0 = (lane < d)       ? (row[lane]       & (NN - 1)) : 0;
        int t1 = (lane + 64 < d)  ? (row[lane + 64]  & (NN - 1)) : 0;
        int t2 = (lane + 128 < d) ? (row[lane + 128] & (NN - 1)) : 0;
        float e0 = (lane < d)       ? lrelu(s1n + s2o[t0]) : -1e30f;
        float e1 = (lane + 64 < d)  ? lrelu(s1n + s2o[t1]) : -1e30f;
        float e2 = (lane + 128 < d) ? lrelu(s1n + s2o[t2]) : -1e30f;
        float m = waveMax(fmaxf(e0, fmaxf(e1, e2)));
        float w0 = (lane < d)       ? __expf(e0 - m) : 0.f;
        float w1 = (lane + 64 < d)  ? __expf(e1 - m) : 0.f;
        float w2 = (lane + 128 < d) ? __expf(e2 - m) : 0.f;
        float den = waveSum(w0 + w1 + w2);
        wts[wid][lane]       = make_float2(w0, __int_as_float(t0 << 4));
        wts[wid][lane + 64]  = make_float2(w1, __int_as_float(t1 << 4));
        wts[wid][lane + 128] = make_float2(w2, __int_as_float(t2 << 4));
        int g2 = lane >> 2, q = lane & 3;
        float a4[4] = {};
        for (int j = g2; j < d; j += 16) {
            float2 p = wts[wid][j];
            float4 v = *(const float4*)(out2 + __float_as_int(p.y) + q * 4);
            a4[0] += p.x * v.x; a4[1] += p.x * v.y;
            a4[2] += p.x * v.z; a4[3] += p.x * v.w;
        }
#pragma unroll
        for (int m2 = 4; m2 <= 32; m2 <<= 1)
#pragma unroll
            for (int i = 0; i < 4; ++i) a4[i] += __shfl_xor(a4[i], m2, 64);
        if (lane < 4)
            *(float4*)&o2s[wid][lane * 4] = make_float4(a4[0], a4[1], a4[2], a4[3]);
        val = o2s[wid][c] / den;
    }
    val += bo[c];
    float mx = val;
#pragma unroll
    for (int m = 8; m >= 1; m >>= 1) mx = fmaxf(mx, __shfl_xor(mx, m, 16));
    float se = __expf(val - mx);
#pragma unroll
    for (int m = 8; m >= 1; m >>= 1) se += __shfl_xor(se, m, 16);
    float res = val - mx - __logf(se);
    if (lane < 16) outp[n * NCLASS + lane] = res;
}

extern "C" void kernel_launch(void* const* d_in, const int* in_sizes, int n_in,
                              void* d_out, int out_size, void* d_ws, size_t ws_size,
                              hipStream_t stream) {
    const void* features = d_in[0];
    const int*  edges    = (const int*)d_in[1];
    const void* W_heads  = d_in[2];
    const void* a_heads  = d_in[3];
    const void* b_heads  = d_in[4];
    const void* W_out    = d_in[5];
    const void* a_out    = d_in[6];
    const void* b_out    = d_in[7];
    int E = in_sizes[1] / 2;

    // ---- workspace layout (4B units) ----
    unsigned int* bits = (unsigned int*)d_ws;                  // NN*NN/32
    int*   deg  = (int*)(bits + (NN * NN / 32));               // NN
    float* cm1  = (float*)(deg + NN);                          // NHEAD*NHID
    float* cm2  = cm1 + NHEAD * NHID;                          // NCLASS (zero region end)
    int*   csr  = (int*)(cm2 + NCLASS);                        // NN*CAP
    float* s1   = (float*)(csr + NN * CAP);                    // NHEAD*NN
    float* s2   = s1 + NHEAD * NN;                             // NHEAD*NN
    float* X    = s2 + NHEAD * NN;                             // NN*NFEAT
    float* out2 = X + (size_t)NN * NFEAT;                      // NN*NCLASS
    float* s1o  = out2 + NN * NCLASS;                          // NN
    float* s2o  = s1o + NN;                                    // NN
    unsigned short* Hb    = (unsigned short*)(s2o + NN);       // NHEAD*NN*NHID bf16
    unsigned short* featb = Hb + (size_t)NHEAD * NN * NHID;    // NN*NFEAT bf16
    unsigned short* Wtb   = featb + (size_t)NN * NFEAT;        // NHEAD*NHID*NFEAT bf16
    float* smallf = (float*)(Wtb + NHEAD * NHID * NFEAT);      // NSMALL fp32
    float* ahf = smallf;
    float* bhf = ahf + SZ2;
    float* Wof = bhf + SZ3;
    float* aof = Wof + SZ4;
    float* bof = aof + SZ5;
    float* outp = (float*)d_out;

    hipLaunchKernelGGL(k_prep, dim3(2048), dim3(256), 0, stream,
                       features, W_heads, a_heads, b_heads, W_out, a_out, b_out,
                       featb, Wtb, smallf, bits);
    hipLaunchKernelGGL(k_build_csr, dim3((E + 255) / 256), dim3(256), 0, stream,
                       edges, E, bits, deg, csr);
    hipLaunchKernelGGL(k_gemm1m, dim3(2048), dim3(256), 0, stream,
                       featb, Wtb, ahf, Hb, s1, s2, cm1);
    hipLaunchKernelGGL(k_attn1, dim3(NN * NHEAD / 4), dim3(256), 0, stream,
                       deg, csr, s1, s2, Hb, bhf, cm1, X);
    hipLaunchKernelGGL(k_gemm2f, dim3(NN / 4), dim3(256), 0, stream,
                       X, Wof, aof, out2, s1o, s2o, cm2);
    hipLaunchKernelGGL(k_attn2, dim3(NN / 4), dim3(256), 0, stream,
                       deg, csr, s1o, s2o, out2, bof, cm2, outp);
}

// Round 13
// 166.206 us; speedup vs baseline: 1.2550x; 1.1640x over previous
//
#include <hip/hip_runtime.h>
#include <hip/hip_bf16.h>

#define NN 4096
#define NFEAT 512
#define NHID 64
#define NHEAD 8
#define NCLASS 16
#define CAP 192
#define LALPHA 0.2f

#define SZ2 (NHEAD*2*NHID)   // a_heads
#define SZ3 (NHEAD*NHID)     // b_heads
#define SZ4 (NFEAT*NCLASS)   // W_out
#define SZ5 (2*NCLASS)       // a_out
#define SZ6 (NCLASS)         // b_out
#define NSMALL (SZ2+SZ3+SZ4+SZ5+SZ6)
#define NZERO (NN*NN/32 + NN + NHEAD*NHID + NCLASS)

typedef __attribute__((ext_vector_type(8))) short bf16x8;
typedef __attribute__((ext_vector_type(4))) float f32x4;
typedef __attribute__((ext_vector_type(8))) unsigned short u16x8;

// ---------- helpers ----------
__device__ __forceinline__ float b2f(unsigned short h) {
    return __uint_as_float(((unsigned int)h) << 16);
}
__device__ __forceinline__ unsigned short f2b(float f) {
    unsigned int u = __float_as_uint(f);
    unsigned int r = (u + 0x7fffu + ((u >> 16) & 1u)) >> 16;
    return (unsigned short)r;
}
__device__ __forceinline__ float waveMax(float v) {
#pragma unroll
    for (int m = 32; m >= 1; m >>= 1) v = fmaxf(v, __shfl_xor(v, m, 64));
    return v;
}
__device__ __forceinline__ float waveSum(float v) {
#pragma unroll
    for (int m = 32; m >= 1; m >>= 1) v += __shfl_xor(v, m, 64);
    return v;
}
__device__ __forceinline__ float lrelu(float e) {
    return e >= 0.f ? e : LALPHA * e;
}

// ---------- prep: W-transpose + edge-bitmap OR + feature/small casts ----------
// blocks [0,128): transpose W_heads -> Wtb bf16 (LDS-tiled)
// blocks [128,128+csb): fire-and-forget atomicOr of edges into bitmap
// blocks [128+csb, grid): grid-stride { features->bf16 (vectorized), smalls->fp32 }
// (bits/deg/cm1/cm2 zeroed by hipMemsetAsync before this launch)
__global__ void __launch_bounds__(256)
k_prep(const void* __restrict__ f, const void* __restrict__ Wh_,
       const void* __restrict__ ah_, const void* __restrict__ bh_,
       const void* __restrict__ Wo_, const void* __restrict__ ao_,
       const void* __restrict__ bo_, const int* __restrict__ e32,
       int E, int csb,
       unsigned short* __restrict__ featb,
       unsigned short* __restrict__ Wtb,
       float* __restrict__ smallf,
       unsigned int* __restrict__ bits) {
    __shared__ int sbf;
    int t = threadIdx.x;
    if (t < 64) {
        unsigned int w = ((const unsigned int*)f)[t];
        unsigned int lo = w & 0xffffu, e = (lo >> 7) & 0xffu;
        unsigned long long bal = __ballot(lo == 0u || (e >= 100u && e <= 140u));
        if (t == 0) sbf = (__popcll(bal) >= 40);
    }
    __syncthreads();
    bool bf = (sbf != 0);
    if (blockIdx.x < 128) {
        __shared__ float tile[64][33];
        int h = blockIdx.x >> 4, k0 = (blockIdx.x & 15) * 32;
        int n = t & 63, kh = t >> 6;
#pragma unroll
        for (int i = 0; i < 8; ++i) {
            int kk = kh * 8 + i;
            int si = (h << 15) + (k0 + kk) * NHID + n;
            float v = bf ? b2f(((const unsigned short*)Wh_)[si])
                         : ((const float*)Wh_)[si];
            tile[n][kk] = v;
        }
        __syncthreads();
        int n2 = t >> 2, kk0 = (t & 3) * 8;
        u16x8 o;
#pragma unroll
        for (int i = 0; i < 8; ++i) o[i] = f2b(tile[n2][kk0 + i]);
        *(u16x8*)&Wtb[(size_t)((h << 6) + n2) * NFEAT + k0 + kk0] = o;
    } else if ((int)blockIdx.x < 128 + csb) {
        // fire-and-forget bitmap OR (no return value -> no atomic round-trip wait)
        __shared__ int s64f;
        if (t < 64) {
            unsigned long long bal = __ballot(e32[2 * t + 1] == 0);
            if (t == 0) s64f = (__popcll(bal) >= 48);
        }
        __syncthreads();
        int i = (blockIdx.x - 128) * 256 + t;
        if (i < E) {
            int s, tt;
            if (s64f) { s = e32[2 * i]; tt = e32[2 * (E + i)]; }
            else      { s = e32[i];     tt = e32[E + i]; }
            s &= (NN - 1); tt &= (NN - 1);
            unsigned int pos = (unsigned int)s * NN + (unsigned int)tt;
            atomicOr(&bits[pos >> 5], 1u << (pos & 31u));
        }
    } else {
        const int NF8 = NN * NFEAT / 8;
        int i = (blockIdx.x - 128 - csb) * 256 + t;
        int stride = (gridDim.x - 128 - csb) * 256;
        const int TOT = NF8 + NSMALL;
        for (; i < TOT; i += stride) {
            if (i < NF8) {
                if (bf) {
                    *(u16x8*)&featb[i * 8] = ((const u16x8*)f)[i];
                } else {
                    float4 lo = ((const float4*)f)[i * 2];
                    float4 hi = ((const float4*)f)[i * 2 + 1];
                    u16x8 o;
                    o[0] = f2b(lo.x); o[1] = f2b(lo.y); o[2] = f2b(lo.z); o[3] = f2b(lo.w);
                    o[4] = f2b(hi.x); o[5] = f2b(hi.y); o[6] = f2b(hi.z); o[7] = f2b(hi.w);
                    *(u16x8*)&featb[i * 8] = o;
                }
            } else {
                int r = i - NF8;
                const void* sp; int off;
                if (r < SZ2)                        { sp = ah_; off = r; }
                else if (r < SZ2 + SZ3)             { sp = bh_; off = r - SZ2; }
                else if (r < SZ2 + SZ3 + SZ4)       { sp = Wo_; off = r - SZ2 - SZ3; }
                else if (r < SZ2 + SZ3 + SZ4 + SZ5) { sp = ao_; off = r - SZ2 - SZ3 - SZ4; }
                else                                { sp = bo_; off = r - SZ2 - SZ3 - SZ4 - SZ5; }
                smallf[r] = bf ? b2f(((const unsigned short*)sp)[off])
                               : ((const float*)sp)[off];
            }
        }
    }
}

// ---------- extract: bitmap row -> sorted CSR row + deg (no atomics) ----------
// wave per node; lane reads 2 words; shuffle prefix-sum; bit-compact.
__global__ void __launch_bounds__(256)
k_extract(const unsigned int* __restrict__ bits,
          int* __restrict__ deg, int* __restrict__ csr) {
    int wid = threadIdx.x >> 6, lane = threadIdx.x & 63;
    int n = blockIdx.x * 4 + wid;
    uint2 w = *(const uint2*)&bits[n * 128 + lane * 2];
    int c = __popc(w.x) + __popc(w.y);
    int incl = c;
#pragma unroll
    for (int off = 1; off < 64; off <<= 1) {
        int u = __shfl_up(incl, off, 64);
        if (lane >= off) incl += u;
    }
    int excl = incl - c;
    int total = __shfl(incl, 63, 64);
    if (lane == 0) deg[n] = total;
    int base = n * CAP;
    int tbase = lane * 64;
    unsigned int x = w.x;
    while (x) {
        int b = __ffs(x) - 1; x &= x - 1;
        if (excl < CAP) csr[base + excl] = tbase + b;
        ++excl;
    }
    unsigned int y = w.y;
    while (y) {
        int b = __ffs(y) - 1; y &= y - 1;
        if (excl < CAP) csr[base + excl] = tbase + 32 + b;
        ++excl;
    }
}

// ---------- MFMA gemm1 + fused scores1 + colmean1 (R10-proven shape) ----------
// grid (32, 8), block 256 (4 waves). Wave computes 32 rows x 64 cols.
__global__ void __launch_bounds__(256)
k_gemm1m(const unsigned short* __restrict__ Ab,   // [NN][NFEAT] bf16
         const unsigned short* __restrict__ Wtb,  // [NHEAD][NHID][NFEAT] bf16
         const float* __restrict__ ah,            // [NHEAD][2*NHID]
         unsigned short* __restrict__ Hb,         // [NHEAD][NN][NHID] bf16
         float* __restrict__ s1, float* __restrict__ s2,   // [NHEAD][NN]
         float* __restrict__ cm1) {               // [NHEAD][NHID]
    __shared__ float cms[64];
    int t = threadIdx.x;
    if (t < 64) cms[t] = 0.f;
    __syncthreads();
    int w = t >> 6, l = t & 63;
    int quad = l >> 4, l16 = l & 15;
    int h = blockIdx.y;
    int m0 = blockIdx.x * 128 + w * 32;
    f32x4 acc[2][4] = {};
    const unsigned short* a0p = Ab + (size_t)(m0 + l16) * NFEAT + quad * 8;
    const unsigned short* a1p = a0p + 16 * NFEAT;
    const unsigned short* bp  = Wtb + ((size_t)h << 15) + (size_t)l16 * NFEAT + quad * 8;
#pragma unroll 4
    for (int k0 = 0; k0 < NFEAT; k0 += 32) {
        bf16x8 a0 = *(const bf16x8*)(a0p + k0);
        bf16x8 a1 = *(const bf16x8*)(a1p + k0);
#pragma unroll
        for (int nt = 0; nt < 4; ++nt) {
            bf16x8 b = *(const bf16x8*)(bp + (size_t)nt * 16 * NFEAT + k0);
            acc[0][nt] = __builtin_amdgcn_mfma_f32_16x16x32_bf16(a0, b, acc[0][nt], 0, 0, 0);
            acc[1][nt] = __builtin_amdgcn_mfma_f32_16x16x32_bf16(a1, b, acc[1][nt], 0, 0, 0);
        }
    }
    const float* av = ah + h * 2 * NHID;
    float p1[2][4] = {}, p2[2][4] = {};
#pragma unroll
    for (int rh = 0; rh < 2; ++rh) {
#pragma unroll
        for (int nt = 0; nt < 4; ++nt) {
            int col = nt * 16 + l16;
            float av1 = av[col], av2 = av[NHID + col];
            float csum = 0.f;
#pragma unroll
            for (int r = 0; r < 4; ++r) {
                float v = acc[rh][nt][r];
                int row = m0 + rh * 16 + quad * 4 + r;
                Hb[(((size_t)h << 12) + row) * NHID + col] = f2b(v);
                p1[rh][r] += v * av1;
                p2[rh][r] += v * av2;
                csum += v;
            }
            atomicAdd(&cms[col], csum);
        }
    }
#pragma unroll
    for (int m = 8; m >= 1; m >>= 1)
#pragma unroll
        for (int rh = 0; rh < 2; ++rh)
#pragma unroll
            for (int r = 0; r < 4; ++r) {
                p1[rh][r] += __shfl_xor(p1[rh][r], m, 64);
                p2[rh][r] += __shfl_xor(p2[rh][r], m, 64);
            }
    if (l16 == 0) {
#pragma unroll
        for (int rh = 0; rh < 2; ++rh)
#pragma unroll
            for (int r = 0; r < 4; ++r) {
                int row = m0 + rh * 16 + quad * 4 + r;
                s1[(h << 12) + row] = p1[rh][r];
                s2[(h << 12) + row] = p2[rh][r];
            }
    }
    __syncthreads();
    if (t < 64) atomicAdd(&cm1[h * NHID + t], cms[t]);
}

// ---------- layer-1: softmax + SpMM(bf16 H) + bias + ELU + concat ----------
// wave per (n,h), head-major order. Gather: 8 lanes/neighbor x u16x8.
__global__ void __launch_bounds__(256)
k_attn1(const int* __restrict__ deg, const int* __restrict__ csr,
        const float* __restrict__ s1, const float* __restrict__ s2,
        const unsigned short* __restrict__ Hb, const float* __restrict__ bh,
        const float* __restrict__ cm1, float* __restrict__ X) {
    __shared__ float2 wts[4][CAP];
    int wid = threadIdx.x >> 6, lane = threadIdx.x & 63;
    int idx = blockIdx.x * 4 + wid;
    int n = idx & (NN - 1), h = idx >> 12;
    int e8 = lane & 7, g = lane >> 3;
    int d = min(deg[n], CAP);
    float acc[8] = {};
    float den = 1.f;
    if (d > 0) {
        float s1n = s1[idx];
        const float* s2h = s2 + ((size_t)h << 12);
        const int* row = csr + (size_t)n * CAP;
        int t0 = (lane < d)       ? (row[lane]       & (NN - 1)) : 0;
        int t1 = (lane + 64 < d)  ? (row[lane + 64]  & (NN - 1)) : 0;
        int t2 = (lane + 128 < d) ? (row[lane + 128] & (NN - 1)) : 0;
        float e0 = (lane < d)       ? lrelu(s1n + s2h[t0]) : -1e30f;
        float e1 = (lane + 64 < d)  ? lrelu(s1n + s2h[t1]) : -1e30f;
        float e2 = (lane + 128 < d) ? lrelu(s1n + s2h[t2]) : -1e30f;
        float m = waveMax(fmaxf(e0, fmaxf(e1, e2)));
        float w0 = (lane < d)       ? __expf(e0 - m) : 0.f;
        float w1 = (lane + 64 < d)  ? __expf(e1 - m) : 0.f;
        float w2 = (lane + 128 < d) ? __expf(e2 - m) : 0.f;
        den = waveSum(w0 + w1 + w2);
        wts[wid][lane]       = make_float2(w0, __int_as_float(t0 << 6));
        wts[wid][lane + 64]  = make_float2(w1, __int_as_float(t1 << 6));
        wts[wid][lane + 128] = make_float2(w2, __int_as_float(t2 << 6));
        const unsigned short* Hp = Hb + (((size_t)h << 12) * NHID) + e8 * 8;
#pragma unroll 2
        for (int j = g; j < d; j += 8) {
            float2 p = wts[wid][j];
            u16x8 v = *(const u16x8*)(Hp + __float_as_int(p.y));
#pragma unroll
            for (int i = 0; i < 8; ++i) acc[i] += p.x * b2f(v[i]);
        }
#pragma unroll
        for (int m2 = 8; m2 <= 32; m2 <<= 1)
#pragma unroll
            for (int i = 0; i < 8; ++i) acc[i] += __shfl_xor(acc[i], m2, 64);
    }
    if (lane < 8) {
        float o[8];
        if (d == 0) {
            const float* c = cm1 + h * NHID + lane * 8;
#pragma unroll
            for (int i = 0; i < 8; ++i) o[i] = c[i] * (1.0f / NN);
        } else {
            float rden = 1.0f / den;
#pragma unroll
            for (int i = 0; i < 8; ++i) o[i] = acc[i] * rden;
        }
        const float* b8p = bh + h * NHID + lane * 8;
#pragma unroll
        for (int i = 0; i < 8; ++i) {
            float v = o[i] + b8p[i];
            o[i] = v > 0.f ? v : __expf(v) - 1.f;     // ELU
        }
        float* xp = &X[(size_t)n * NFEAT + h * NHID + lane * 8];
        *(float4*)xp       = make_float4(o[0], o[1], o[2], o[3]);
        *(float4*)(xp + 4) = make_float4(o[4], o[5], o[6], o[7]);
    }
}

// ---------- gemm2 + fused scores2 + colmean2 ----------
__global__ void __launch_bounds__(256)
k_gemm2f(const float* __restrict__ X, const float* __restrict__ Wo,
         const float* __restrict__ ao, float* __restrict__ out2,
         float* __restrict__ s1o, float* __restrict__ s2o,
         float* __restrict__ cm2) {
    __shared__ float cms[16];
    int t = threadIdx.x;
    if (t < 16) cms[t] = 0.f;
    __syncthreads();
    int wid = t >> 6, lane = t & 63;
    int n = blockIdx.x * 4 + wid;
    int c = lane & 15, sub = lane >> 4;
    const float* xr = X + (size_t)n * NFEAT + sub * 128;
    const float* wr = Wo + sub * 128 * NCLASS + c;
    float acc = 0.f;
#pragma unroll 8
    for (int kk = 0; kk < 128; ++kk) acc += xr[kk] * wr[kk * NCLASS];
    acc += __shfl_xor(acc, 16, 64);
    acc += __shfl_xor(acc, 32, 64);
    if (lane < 16) out2[n * NCLASS + c] = acc;
    float r1 = acc * ao[c], r2 = acc * ao[NCLASS + c];
#pragma unroll
    for (int m = 8; m >= 1; m >>= 1) {
        r1 += __shfl_xor(r1, m, 16);
        r2 += __shfl_xor(r2, m, 16);
    }
    if (lane == 0) { s1o[n] = r1; s2o[n] = r2; }
    if (lane < 16) atomicAdd(&cms[c], acc);
    __syncthreads();
    if (t < 16) atomicAdd(&cm2[t], cms[t]);
}

// ---------- layer-2: softmax + SpMM + bias + log_softmax ----------
__global__ void __launch_bounds__(256)
k_attn2(const int* __restrict__ deg, const int* __restrict__ csr,
        const float* __restrict__ s1o, const float* __restrict__ s2o,
        const float* __restrict__ out2, const float* __restrict__ bo,
        const float* __restrict__ cm2, float* __restrict__ outp) {
    __shared__ float2 wts[4][CAP];
    __shared__ float o2s[4][16];
    int wid = threadIdx.x >> 6, lane = threadIdx.x & 63;
    int n = blockIdx.x * 4 + wid;
    int c = lane & 15;
    int d = min(deg[n], CAP);
    float val;
    if (d == 0) {
        val = cm2[c] * (1.0f / NN);
    } else {
        float s1n = s1o[n];
        const int* row = csr + (size_t)n * CAP;
        int t0 = (lane < d)       ? (row[lane]       & (NN - 1)) : 0;
        int t1 = (lane + 64 < d)  ? (row[lane + 64]  & (NN - 1)) : 0;
        int t2 = (lane + 128 < d) ? (row[lane + 128] & (NN - 1)) : 0;
        float e0 = (lane < d)       ? lrelu(s1n + s2o[t0]) : -1e30f;
        float e1 = (lane + 64 < d)  ? lrelu(s1n + s2o[t1]) : -1e30f;
        float e2 = (lane + 128 < d) ? lrelu(s1n + s2o[t2]) : -1e30f;
        float m = waveMax(fmaxf(e0, fmaxf(e1, e2)));
        float w0 = (lane < d)       ? __expf(e0 - m) : 0.f;
        float w1 = (lane + 64 < d)  ? __expf(e1 - m) : 0.f;
        float w2 = (lane + 128 < d) ? __expf(e2 - m) : 0.f;
        float den = waveSum(w0 + w1 + w2);
        wts[wid][lane]       = make_float2(w0, __int_as_float(t0 << 4));
        wts[wid][lane + 64]  = make_float2(w1, __int_as_float(t1 << 4));
        wts[wid][lane + 128] = make_float2(w2, __int_as_float(t2 << 4));
        int g2 = lane >> 2, q = lane & 3;
        float a4[4] = {};
        for (int j = g2; j < d; j += 16) {
            float2 p = wts[wid][j];
            float4 v = *(const float4*)(out2 + __float_as_int(p.y) + q * 4);
            a4[0] += p.x * v.x; a4[1] += p.x * v.y;
            a4[2] += p.x * v.z; a4[3] += p.x * v.w;
        }
#pragma unroll
        for (int m2 = 4; m2 <= 32; m2 <<= 1)
#pragma unroll
            for (int i = 0; i < 4; ++i) a4[i] += __shfl_xor(a4[i], m2, 64);
        if (lane < 4)
            *(float4*)&o2s[wid][lane * 4] = make_float4(a4[0], a4[1], a4[2], a4[3]);
        val = o2s[wid][c] / den;
    }
    val += bo[c];
    float mx = val;
#pragma unroll
    for (int m = 8; m >= 1; m >>= 1) mx = fmaxf(mx, __shfl_xor(mx, m, 16));
    float se = __expf(val - mx);
#pragma unroll
    for (int m = 8; m >= 1; m >>= 1) se += __shfl_xor(se, m, 16);
    float res = val - mx - __logf(se);
    if (lane < 16) outp[n * NCLASS + lane] = res;
}

extern "C" void kernel_launch(void* const* d_in, const int* in_sizes, int n_in,
                              void* d_out, int out_size, void* d_ws, size_t ws_size,
                              hipStream_t stream) {
    const void* features = d_in[0];
    const int*  edges    = (const int*)d_in[1];
    const void* W_heads  = d_in[2];
    const void* a_heads  = d_in[3];
    const void* b_heads  = d_in[4];
    const void* W_out    = d_in[5];
    const void* a_out    = d_in[6];
    const void* b_out    = d_in[7];
    int E = in_sizes[1] / 2;

    // ---- workspace layout (4B units) ----
    unsigned int* bits = (unsigned int*)d_ws;                  // NN*NN/32
    int*   deg  = (int*)(bits + (NN * NN / 32));               // NN
    float* cm1  = (float*)(deg + NN);                          // NHEAD*NHID
    float* cm2  = cm1 + NHEAD * NHID;                          // NCLASS (zero region end)
    int*   csr  = (int*)(cm2 + NCLASS);                        // NN*CAP
    float* s1   = (float*)(csr + NN * CAP);                    // NHEAD*NN
    float* s2   = s1 + NHEAD * NN;                             // NHEAD*NN
    float* X    = s2 + NHEAD * NN;                             // NN*NFEAT
    float* out2 = X + (size_t)NN * NFEAT;                      // NN*NCLASS
    float* s1o  = out2 + NN * NCLASS;                          // NN
    float* s2o  = s1o + NN;                                    // NN
    unsigned short* Hb    = (unsigned short*)(s2o + NN);       // NHEAD*NN*NHID bf16
    unsigned short* featb = Hb + (size_t)NHEAD * NN * NHID;    // NN*NFEAT bf16
    unsigned short* Wtb   = featb + (size_t)NN * NFEAT;        // NHEAD*NHID*NFEAT bf16
    float* smallf = (float*)(Wtb + NHEAD * NHID * NFEAT);      // NSMALL fp32
    float* ahf = smallf;
    float* bhf = ahf + SZ2;
    float* Wof = bhf + SZ3;
    float* aof = Wof + SZ4;
    float* bof = aof + SZ5;
    float* outp = (float*)d_out;

    int csb = (E + 255) / 256;
    hipMemsetAsync(d_ws, 0, (size_t)NZERO * 4, stream);        // bits+deg+cm1+cm2
    hipLaunchKernelGGL(k_prep, dim3(128 + csb + 896), dim3(256), 0, stream,
                       features, W_heads, a_heads, b_heads, W_out, a_out, b_out,
                       edges, E, csb, featb, Wtb, smallf, bits);
    hipLaunchKernelGGL(k_extract, dim3(NN / 4), dim3(256), 0, stream,
                       bits, deg, csr);
    hipLaunchKernelGGL(k_gemm1m, dim3(32, NHEAD), dim3(256), 0, stream,
                       featb, Wtb, ahf, Hb, s1, s2, cm1);
    hipLaunchKernelGGL(k_attn1, dim3(NN * NHEAD / 4), dim3(256), 0, stream,
                       deg, csr, s1, s2, Hb, bhf, cm1, X);
    hipLaunchKernelGGL(k_gemm2f, dim3(NN / 4), dim3(256), 0, stream,
                       X, Wof, aof, out2, s1o, s2o, cm2);
    hipLaunchKernelGGL(k_attn2, dim3(NN / 4), dim3(256), 0, stream,
                       deg, csr, s1o, s2o, out2, bof, cm2, outp);
}

// Round 14
// 163.541 us; speedup vs baseline: 1.2754x; 1.0163x over previous
//
#include <hip/hip_runtime.h>
#include <hip/hip_bf16.h>

#define NN 4096
#define NFEAT 512
#define NHID 64
#define NHEAD 8
#define NCLASS 16
#define CAP 192
#define LALPHA 0.2f

#define SZ2 (NHEAD*2*NHID)   // a_heads
#define SZ3 (NHEAD*NHID)     // b_heads
#define SZ4 (NFEAT*NCLASS)   // W_out
#define SZ5 (2*NCLASS)       // a_out
#define SZ6 (NCLASS)         // b_out
#define NSMALL (SZ2+SZ3+SZ4+SZ5+SZ6)
#define NZERO (NN*NN/32 + NN + NHEAD*NHID + NCLASS)

typedef __attribute__((ext_vector_type(8))) short bf16x8;
typedef __attribute__((ext_vector_type(4))) float f32x4;
typedef __attribute__((ext_vector_type(8))) unsigned short u16x8;

// ---------- helpers ----------
__device__ __forceinline__ float b2f(unsigned short h) {
    return __uint_as_float(((unsigned int)h) << 16);
}
__device__ __forceinline__ unsigned short f2b(float f) {
    unsigned int u = __float_as_uint(f);
    unsigned int r = (u + 0x7fffu + ((u >> 16) & 1u)) >> 16;
    return (unsigned short)r;
}
__device__ __forceinline__ float waveMax(float v) {
#pragma unroll
    for (int m = 32; m >= 1; m >>= 1) v = fmaxf(v, __shfl_xor(v, m, 64));
    return v;
}
__device__ __forceinline__ float waveSum(float v) {
#pragma unroll
    for (int m = 32; m >= 1; m >>= 1) v += __shfl_xor(v, m, 64);
    return v;
}
__device__ __forceinline__ float lrelu(float e) {
    return e >= 0.f ? e : LALPHA * e;
}

// ---------- prep: W-transpose + edge-bitmap OR + feature/small casts ----------
__global__ void __launch_bounds__(256)
k_prep(const void* __restrict__ f, const void* __restrict__ Wh_,
       const void* __restrict__ ah_, const void* __restrict__ bh_,
       const void* __restrict__ Wo_, const void* __restrict__ ao_,
       const void* __restrict__ bo_, const int* __restrict__ e32,
       int E, int csb,
       unsigned short* __restrict__ featb,
       unsigned short* __restrict__ Wtb,
       float* __restrict__ smallf,
       unsigned int* __restrict__ bits) {
    __shared__ int sbf;
    int t = threadIdx.x;
    if (t < 64) {
        unsigned int w = ((const unsigned int*)f)[t];
        unsigned int lo = w & 0xffffu, e = (lo >> 7) & 0xffu;
        unsigned long long bal = __ballot(lo == 0u || (e >= 100u && e <= 140u));
        if (t == 0) sbf = (__popcll(bal) >= 40);
    }
    __syncthreads();
    bool bf = (sbf != 0);
    if (blockIdx.x < 128) {
        __shared__ float tile[64][33];
        int h = blockIdx.x >> 4, k0 = (blockIdx.x & 15) * 32;
        int n = t & 63, kh = t >> 6;
#pragma unroll
        for (int i = 0; i < 8; ++i) {
            int kk = kh * 8 + i;
            int si = (h << 15) + (k0 + kk) * NHID + n;
            float v = bf ? b2f(((const unsigned short*)Wh_)[si])
                         : ((const float*)Wh_)[si];
            tile[n][kk] = v;
        }
        __syncthreads();
        int n2 = t >> 2, kk0 = (t & 3) * 8;
        u16x8 o;
#pragma unroll
        for (int i = 0; i < 8; ++i) o[i] = f2b(tile[n2][kk0 + i]);
        *(u16x8*)&Wtb[(size_t)((h << 6) + n2) * NFEAT + k0 + kk0] = o;
    } else if ((int)blockIdx.x < 128 + csb) {
        // fire-and-forget bitmap OR (no return value -> no atomic round-trip wait)
        __shared__ int s64f;
        if (t < 64) {
            unsigned long long bal = __ballot(e32[2 * t + 1] == 0);
            if (t == 0) s64f = (__popcll(bal) >= 48);
        }
        __syncthreads();
        int i = (blockIdx.x - 128) * 256 + t;
        if (i < E) {
            int s, tt;
            if (s64f) { s = e32[2 * i]; tt = e32[2 * (E + i)]; }
            else      { s = e32[i];     tt = e32[E + i]; }
            s &= (NN - 1); tt &= (NN - 1);
            unsigned int pos = (unsigned int)s * NN + (unsigned int)tt;
            atomicOr(&bits[pos >> 5], 1u << (pos & 31u));
        }
    } else {
        const int NF8 = NN * NFEAT / 8;
        int i = (blockIdx.x - 128 - csb) * 256 + t;
        int stride = (gridDim.x - 128 - csb) * 256;
        const int TOT = NF8 + NSMALL;
        for (; i < TOT; i += stride) {
            if (i < NF8) {
                if (bf) {
                    *(u16x8*)&featb[i * 8] = ((const u16x8*)f)[i];
                } else {
                    float4 lo = ((const float4*)f)[i * 2];
                    float4 hi = ((const float4*)f)[i * 2 + 1];
                    u16x8 o;
                    o[0] = f2b(lo.x); o[1] = f2b(lo.y); o[2] = f2b(lo.z); o[3] = f2b(lo.w);
                    o[4] = f2b(hi.x); o[5] = f2b(hi.y); o[6] = f2b(hi.z); o[7] = f2b(hi.w);
                    *(u16x8*)&featb[i * 8] = o;
                }
            } else {
                int r = i - NF8;
                const void* sp; int off;
                if (r < SZ2)                        { sp = ah_; off = r; }
                else if (r < SZ2 + SZ3)             { sp = bh_; off = r - SZ2; }
                else if (r < SZ2 + SZ3 + SZ4)       { sp = Wo_; off = r - SZ2 - SZ3; }
                else if (r < SZ2 + SZ3 + SZ4 + SZ5) { sp = ao_; off = r - SZ2 - SZ3 - SZ4; }
                else                                { sp = bo_; off = r - SZ2 - SZ3 - SZ4 - SZ5; }
                smallf[r] = bf ? b2f(((const unsigned short*)sp)[off])
                               : ((const float*)sp)[off];
            }
        }
    }
}

// ---------- merged: MFMA gemm1 (blocks [0,256)) + bitmap extract (blocks [256,1280)) ----------
// Both depend only on k_prep; independent of each other. GEMM blocks dispatched FIRST
// so their latency-bound waves start immediately; extract fills remaining capacity.
__global__ void __launch_bounds__(256)
k_gemm_ext(const unsigned short* __restrict__ Ab,   // [NN][NFEAT] bf16
           const unsigned short* __restrict__ Wtb,  // [NHEAD][NHID][NFEAT] bf16
           const float* __restrict__ ah,            // [NHEAD][2*NHID]
           unsigned short* __restrict__ Hb,         // [NHEAD][NN][NHID] bf16
           float* __restrict__ s1, float* __restrict__ s2,   // [NHEAD][NN]
           float* __restrict__ cm1,                 // [NHEAD][NHID]
           const unsigned int* __restrict__ bits,
           int* __restrict__ deg, int* __restrict__ csr) {
    int t = threadIdx.x;
    if (blockIdx.x >= 256) {
        // ---- extract: bitmap row -> sorted CSR row + deg (no atomics) ----
        int wid = t >> 6, lane = t & 63;
        int n = (blockIdx.x - 256) * 4 + wid;
        uint2 w = *(const uint2*)&bits[n * 128 + lane * 2];
        int c = __popc(w.x) + __popc(w.y);
        int incl = c;
#pragma unroll
        for (int off = 1; off < 64; off <<= 1) {
            int u = __shfl_up(incl, off, 64);
            if (lane >= off) incl += u;
        }
        int excl = incl - c;
        int total = __shfl(incl, 63, 64);
        if (lane == 0) deg[n] = total;
        int base = n * CAP;
        int tbase = lane * 64;
        unsigned int x = w.x;
        while (x) {
            int b = __ffs(x) - 1; x &= x - 1;
            if (excl < CAP) csr[base + excl] = tbase + b;
            ++excl;
        }
        unsigned int y = w.y;
        while (y) {
            int b = __ffs(y) - 1; y &= y - 1;
            if (excl < CAP) csr[base + excl] = tbase + 32 + b;
            ++excl;
        }
        return;
    }
    // ---- gemm1: b in [0,256), h = b>>5, bx = b&31 ----
    __shared__ float cms[64];
    if (t < 64) cms[t] = 0.f;
    __syncthreads();
    int w = t >> 6, l = t & 63;
    int quad = l >> 4, l16 = l & 15;
    int h = blockIdx.x >> 5;
    int m0 = (blockIdx.x & 31) * 128 + w * 32;
    f32x4 acc[2][4] = {};
    const unsigned short* a0p = Ab + (size_t)(m0 + l16) * NFEAT + quad * 8;
    const unsigned short* a1p = a0p + 16 * NFEAT;
    const unsigned short* bp  = Wtb + ((size_t)h << 15) + (size_t)l16 * NFEAT + quad * 8;
#pragma unroll 4
    for (int k0 = 0; k0 < NFEAT; k0 += 32) {
        bf16x8 a0 = *(const bf16x8*)(a0p + k0);
        bf16x8 a1 = *(const bf16x8*)(a1p + k0);
#pragma unroll
        for (int nt = 0; nt < 4; ++nt) {
            bf16x8 b = *(const bf16x8*)(bp + (size_t)nt * 16 * NFEAT + k0);
            acc[0][nt] = __builtin_amdgcn_mfma_f32_16x16x32_bf16(a0, b, acc[0][nt], 0, 0, 0);
            acc[1][nt] = __builtin_amdgcn_mfma_f32_16x16x32_bf16(a1, b, acc[1][nt], 0, 0, 0);
        }
    }
    const float* av = ah + h * 2 * NHID;
    float p1[2][4] = {}, p2[2][4] = {};
#pragma unroll
    for (int rh = 0; rh < 2; ++rh) {
#pragma unroll
        for (int nt = 0; nt < 4; ++nt) {
            int col = nt * 16 + l16;
            float av1 = av[col], av2 = av[NHID + col];
            float csum = 0.f;
#pragma unroll
            for (int r = 0; r < 4; ++r) {
                float v = acc[rh][nt][r];
                int row = m0 + rh * 16 + quad * 4 + r;
                Hb[(((size_t)h << 12) + row) * NHID + col] = f2b(v);
                p1[rh][r] += v * av1;
                p2[rh][r] += v * av2;
                csum += v;
            }
            atomicAdd(&cms[col], csum);
        }
    }
#pragma unroll
    for (int m = 8; m >= 1; m >>= 1)
#pragma unroll
        for (int rh = 0; rh < 2; ++rh)
#pragma unroll
            for (int r = 0; r < 4; ++r) {
                p1[rh][r] += __shfl_xor(p1[rh][r], m, 64);
                p2[rh][r] += __shfl_xor(p2[rh][r], m, 64);
            }
    if (l16 == 0) {
#pragma unroll
        for (int rh = 0; rh < 2; ++rh)
#pragma unroll
            for (int r = 0; r < 4; ++r) {
                int row = m0 + rh * 16 + quad * 4 + r;
                s1[(h << 12) + row] = p1[rh][r];
                s2[(h << 12) + row] = p2[rh][r];
            }
    }
    __syncthreads();
    if (t < 64) atomicAdd(&cm1[h * NHID + t], cms[t]);
}

// ---------- layer-1: softmax + SpMM(bf16 H) + bias + ELU + concat ----------
// wave per (n,h), head-major order. Gather: 8 lanes/neighbor x u16x8.
__global__ void __launch_bounds__(256)
k_attn1(const int* __restrict__ deg, const int* __restrict__ csr,
        const float* __restrict__ s1, const float* __restrict__ s2,
        const unsigned short* __restrict__ Hb, const float* __restrict__ bh,
        const float* __restrict__ cm1, float* __restrict__ X) {
    __shared__ float2 wts[4][CAP];
    int wid = threadIdx.x >> 6, lane = threadIdx.x & 63;
    int idx = blockIdx.x * 4 + wid;
    int n = idx & (NN - 1), h = idx >> 12;
    int e8 = lane & 7, g = lane >> 3;
    int d = min(deg[n], CAP);
    float acc[8] = {};
    float den = 1.f;
    if (d > 0) {
        float s1n = s1[idx];
        const float* s2h = s2 + ((size_t)h << 12);
        const int* row = csr + (size_t)n * CAP;
        int t0 = (lane < d)       ? (row[lane]       & (NN - 1)) : 0;
        int t1 = (lane + 64 < d)  ? (row[lane + 64]  & (NN - 1)) : 0;
        int t2 = (lane + 128 < d) ? (row[lane + 128] & (NN - 1)) : 0;
        float e0 = (lane < d)       ? lrelu(s1n + s2h[t0]) : -1e30f;
        float e1 = (lane + 64 < d)  ? lrelu(s1n + s2h[t1]) : -1e30f;
        float e2 = (lane + 128 < d) ? lrelu(s1n + s2h[t2]) : -1e30f;
        float m = waveMax(fmaxf(e0, fmaxf(e1, e2)));
        float w0 = (lane < d)       ? __expf(e0 - m) : 0.f;
        float w1 = (lane + 64 < d)  ? __expf(e1 - m) : 0.f;
        float w2 = (lane + 128 < d) ? __expf(e2 - m) : 0.f;
        den = waveSum(w0 + w1 + w2);
        wts[wid][lane]       = make_float2(w0, __int_as_float(t0 << 6));
        wts[wid][lane + 64]  = make_float2(w1, __int_as_float(t1 << 6));
        wts[wid][lane + 128] = make_float2(w2, __int_as_float(t2 << 6));
        const unsigned short* Hp = Hb + (((size_t)h << 12) * NHID) + e8 * 8;
#pragma unroll 2
        for (int j = g; j < d; j += 8) {
            float2 p = wts[wid][j];
            u16x8 v = *(const u16x8*)(Hp + __float_as_int(p.y));
#pragma unroll
            for (int i = 0; i < 8; ++i) acc[i] += p.x * b2f(v[i]);
        }
#pragma unroll
        for (int m2 = 8; m2 <= 32; m2 <<= 1)
#pragma unroll
            for (int i = 0; i < 8; ++i) acc[i] += __shfl_xor(acc[i], m2, 64);
    }
    if (lane < 8) {
        float o[8];
        if (d == 0) {
            const float* c = cm1 + h * NHID + lane * 8;
#pragma unroll
            for (int i = 0; i < 8; ++i) o[i] = c[i] * (1.0f / NN);
        } else {
            float rden = 1.0f / den;
#pragma unroll
            for (int i = 0; i < 8; ++i) o[i] = acc[i] * rden;
        }
        const float* b8p = bh + h * NHID + lane * 8;
#pragma unroll
        for (int i = 0; i < 8; ++i) {
            float v = o[i] + b8p[i];
            o[i] = v > 0.f ? v : __expf(v) - 1.f;     // ELU
        }
        float* xp = &X[(size_t)n * NFEAT + h * NHID + lane * 8];
        *(float4*)xp       = make_float4(o[0], o[1], o[2], o[3]);
        *(float4*)(xp + 4) = make_float4(o[4], o[5], o[6], o[7]);
    }
}

// ---------- gemm2 + fused scores2 + colmean2 ----------
__global__ void __launch_bounds__(256)
k_gemm2f(const float* __restrict__ X, const float* __restrict__ Wo,
         const float* __restrict__ ao, float* __restrict__ out2,
         float* __restrict__ s1o, float* __restrict__ s2o,
         float* __restrict__ cm2) {
    __shared__ float cms[16];
    int t = threadIdx.x;
    if (t < 16) cms[t] = 0.f;
    __syncthreads();
    int wid = t >> 6, lane = t & 63;
    int n = blockIdx.x * 4 + wid;
    int c = lane & 15, sub = lane >> 4;
    const float* xr = X + (size_t)n * NFEAT + sub * 128;
    const float* wr = Wo + sub * 128 * NCLASS + c;
    float acc = 0.f;
#pragma unroll 8
    for (int kk = 0; kk < 128; ++kk) acc += xr[kk] * wr[kk * NCLASS];
    acc += __shfl_xor(acc, 16, 64);
    acc += __shfl_xor(acc, 32, 64);
    if (lane < 16) out2[n * NCLASS + c] = acc;
    float r1 = acc * ao[c], r2 = acc * ao[NCLASS + c];
#pragma unroll
    for (int m = 8; m >= 1; m >>= 1) {
        r1 += __shfl_xor(r1, m, 16);
        r2 += __shfl_xor(r2, m, 16);
    }
    if (lane == 0) { s1o[n] = r1; s2o[n] = r2; }
    if (lane < 16) atomicAdd(&cms[c], acc);
    __syncthreads();
    if (t < 16) atomicAdd(&cm2[t], cms[t]);
}

// ---------- layer-2: softmax + SpMM + bias + log_softmax ----------
__global__ void __launch_bounds__(256)
k_attn2(const int* __restrict__ deg, const int* __restrict__ csr,
        const float* __restrict__ s1o, const float* __restrict__ s2o,
        const float* __restrict__ out2, const float* __restrict__ bo,
        const float* __restrict__ cm2, float* __restrict__ outp) {
    __shared__ float2 wts[4][CAP];
    __shared__ float o2s[4][16];
    int wid = threadIdx.x >> 6, lane = threadIdx.x & 63;
    int n = blockIdx.x * 4 + wid;
    int c = lane & 15;
    int d = min(deg[n], CAP);
    float val;
    if (d == 0) {
        val = cm2[c] * (1.0f / NN);
    } else {
        float s1n = s1o[n];
        const int* row = csr + (size_t)n * CAP;
        int t0 = (lane < d)       ? (row[lane]       & (NN - 1)) : 0;
        int t1 = (lane + 64 < d)  ? (row[lane + 64]  & (NN - 1)) : 0;
        int t2 = (lane + 128 < d) ? (row[lane + 128] & (NN - 1)) : 0;
        float e0 = (lane < d)       ? lrelu(s1n + s2o[t0]) : -1e30f;
        float e1 = (lane + 64 < d)  ? lrelu(s1n + s2o[t1]) : -1e30f;
        float e2 = (lane + 128 < d) ? lrelu(s1n + s2o[t2]) : -1e30f;
        float m = waveMax(fmaxf(e0, fmaxf(e1, e2)));
        float w0 = (lane < d)       ? __expf(e0 - m) : 0.f;
        float w1 = (lane + 64 < d)  ? __expf(e1 - m) : 0.f;
        float w2 = (lane + 128 < d) ? __expf(e2 - m) : 0.f;
        float den = waveSum(w0 + w1 + w2);
        wts[wid][lane]       = make_float2(w0, __int_as_float(t0 << 4));
        wts[wid][lane + 64]  = make_float2(w1, __int_as_float(t1 << 4));
        wts[wid][lane + 128] = make_float2(w2, __int_as_float(t2 << 4));
        int g2 = lane >> 2, q = lane & 3;
        float a4[4] = {};
        for (int j = g2; j < d; j += 16) {
            float2 p = wts[wid][j];
            float4 v = *(const float4*)(out2 + __float_as_int(p.y) + q * 4);
            a4[0] += p.x * v.x; a4[1] += p.x * v.y;
            a4[2] += p.x * v.z; a4[3] += p.x * v.w;
        }
#pragma unroll
        for (int m2 = 4; m2 <= 32; m2 <<= 1)
#pragma unroll
            for (int i = 0; i < 4; ++i) a4[i] += __shfl_xor(a4[i], m2, 64);
        if (lane < 4)
            *(float4*)&o2s[wid][lane * 4] = make_float4(a4[0], a4[1], a4[2], a4[3]);
        val = o2s[wid][c] / den;
    }
    val += bo[c];
    float mx = val;
#pragma unroll
    for (int m = 8; m >= 1; m >>= 1) mx = fmaxf(mx, __shfl_xor(mx, m, 16));
    float se = __expf(val - mx);
#pragma unroll
    for (int m = 8; m >= 1; m >>= 1) se += __shfl_xor(se, m, 16);
    float res = val - mx - __logf(se);
    if (lane < 16) outp[n * NCLASS + lane] = res;
}

extern "C" void kernel_launch(void* const* d_in, const int* in_sizes, int n_in,
                              void* d_out, int out_size, void* d_ws, size_t ws_size,
                              hipStream_t stream) {
    const void* features = d_in[0];
    const int*  edges    = (const int*)d_in[1];
    const void* W_heads  = d_in[2];
    const void* a_heads  = d_in[3];
    const void* b_heads  = d_in[4];
    const void* W_out    = d_in[5];
    const void* a_out    = d_in[6];
    const void* b_out    = d_in[7];
    int E = in_sizes[1] / 2;

    // ---- workspace layout (4B units) ----
    unsigned int* bits = (unsigned int*)d_ws;                  // NN*NN/32
    int*   deg  = (int*)(bits + (NN * NN / 32));               // NN
    float* cm1  = (float*)(deg + NN);                          // NHEAD*NHID
    float* cm2  = cm1 + NHEAD * NHID;                          // NCLASS (zero region end)
    int*   csr  = (int*)(cm2 + NCLASS);                        // NN*CAP
    float* s1   = (float*)(csr + NN * CAP);                    // NHEAD*NN
    float* s2   = s1 + NHEAD * NN;                             // NHEAD*NN
    float* X    = s2 + NHEAD * NN;                             // NN*NFEAT
    float* out2 = X + (size_t)NN * NFEAT;                      // NN*NCLASS
    float* s1o  = out2 + NN * NCLASS;                          // NN
    float* s2o  = s1o + NN;                                    // NN
    unsigned short* Hb    = (unsigned short*)(s2o + NN);       // NHEAD*NN*NHID bf16
    unsigned short* featb = Hb + (size_t)NHEAD * NN * NHID;    // NN*NFEAT bf16
    unsigned short* Wtb   = featb + (size_t)NN * NFEAT;        // NHEAD*NHID*NFEAT bf16
    float* smallf = (float*)(Wtb + NHEAD * NHID * NFEAT);      // NSMALL fp32
    float* ahf = smallf;
    float* bhf = ahf + SZ2;
    float* Wof = bhf + SZ3;
    float* aof = Wof + SZ4;
    float* bof = aof + SZ5;
    float* outp = (float*)d_out;

    int csb = (E + 255) / 256;
    hipMemsetAsync(d_ws, 0, (size_t)NZERO * 4, stream);        // bits+deg+cm1+cm2
    hipLaunchKernelGGL(k_prep, dim3(128 + csb + 896), dim3(256), 0, stream,
                       features, W_heads, a_heads, b_heads, W_out, a_out, b_out,
                       edges, E, csb, featb, Wtb, smallf, bits);
    hipLaunchKernelGGL(k_gemm_ext, dim3(256 + NN / 4), dim3(256), 0, stream,
                       featb, Wtb, ahf, Hb, s1, s2, cm1, bits, deg, csr);
    hipLaunchKernelGGL(k_attn1, dim3(NN * NHEAD / 4), dim3(256), 0, stream,
                       deg, csr, s1, s2, Hb, bhf, cm1, X);
    hipLaunchKernelGGL(k_gemm2f, dim3(NN / 4), dim3(256), 0, stream,
                       X, Wof, aof, out2, s1o, s2o, cm2);
    hipLaunchKernelGGL(k_attn2, dim3(NN / 4), dim3(256), 0, stream,
                       deg, csr, s1o, s2o, out2, bof, cm2, outp);
}